// Round 1
// baseline (470.384 us; speedup 1.0000x reference)
//
#include <hip/hip_runtime.h>
#include <hip/hip_bf16.h>

#define B_ROWS 32768
#define E_DIM  256
#define HH_DIM 128
#define HN_DIM 256
#define NDEPTH 5

typedef float  f32x4   __attribute__((ext_vector_type(4)));
typedef short  bf16x8  __attribute__((ext_vector_type(8)));
typedef unsigned short ushort8 __attribute__((ext_vector_type(8)));

__device__ __forceinline__ unsigned short f2bf(float f) {
    unsigned int u = __builtin_bit_cast(unsigned int, f);
    return (unsigned short)((u + 0x7FFFu + ((u >> 16) & 1u)) >> 16);
}

__device__ __forceinline__ float fast_sig(float x) {
    x = fminf(fmaxf(x, -30.f), 30.f);
    return 1.0f / (1.0f + __expf(-x));
}
__device__ __forceinline__ float fast_tanh(float x) {
    x = fminf(fmaxf(x, -15.f), 15.f);
    float e = __expf(2.0f * x);
    return (e - 1.0f) / (e + 1.0f);
}

// ---- weight transpose + bf16 convert: in [d][K][N] f32 -> out [d][N][K] bf16 ----
__global__ void wtrans_kernel(const float* __restrict__ in, unsigned short* __restrict__ out,
                              int K, int N) {
    __shared__ float tile[32][33];
    int n0 = blockIdx.x * 32, k0 = blockIdx.y * 32, d = blockIdx.z;
    in  += (size_t)d * K * N;
    out += (size_t)d * K * N;
    int tx = threadIdx.x, ty = threadIdx.y; // (32,8)
#pragma unroll
    for (int j = 0; j < 32; j += 8)
        tile[ty + j][tx] = in[(size_t)(k0 + ty + j) * N + n0 + tx];
    __syncthreads();
#pragma unroll
    for (int j = 0; j < 32; j += 8)
        out[(size_t)(n0 + ty + j) * K + k0 + tx] = f2bf(tile[tx][ty + j]);
}

// ---- fused HyperRHN kernel: one block = 64 rows x one depth ----
__global__ void __launch_bounds__(256, 2)
hyper_rhn_kernel(const float* __restrict__ x,
                 const float* __restrict__ sHyper,
                 const float* __restrict__ sNetwork,
                 const float* __restrict__ b_inp_h,
                 const float* __restrict__ b_cell_h,
                 const float* __restrict__ b_inp_n,
                 const float* __restrict__ b_cell_n,
                 const float* __restrict__ b_up,
                 const unsigned short* __restrict__ wtCellH,  // [5][256][128]
                 const unsigned short* __restrict__ wtUp,     // [5][256][128]
                 const unsigned short* __restrict__ wtCellN,  // [5][512][256]
                 const unsigned short* __restrict__ wtInpH,   // [256][256]
                 const unsigned short* __restrict__ wtInpN,   // [512][256]
                 float* __restrict__ outMain,
                 float* __restrict__ outSH,
                 float* __restrict__ outSN) {
    __shared__ unsigned short Asub[64 * 64];     // staged A chunk, XOR-swizzled
    __shared__ unsigned short sHlds[64 * 128];   // gated hyper state (bf16), XOR-swizzled

    const int l   = blockIdx.y;
    const int r0  = blockIdx.x * 64;
    const int tid = threadIdx.x;
    const int w    = tid >> 6;     // wave 0..3
    const int lane = tid & 63;
    const int lr   = lane & 15;
    const int q    = lane >> 4;    // quarter 0..3

    const int srow = tid >> 2, sseg = tid & 3;   // staging decomposition

    // ================= P1: WsH = sHyper[l] @ W_cell_h[l] (+ x @ W_inp_h at l==0) =================
    f32x4 accH[4][4] = {};   // [row-frag][cg-local]; cg = w + cgl*4
    const int nkb1 = (l == 0) ? 6 : 2;
    for (int kb = 0; kb < nkb1; ++kb) {
        __syncthreads();
        {
            const float* src = (kb < 2)
                ? sHyper + ((size_t)l * B_ROWS + r0 + srow) * HH_DIM + kb * 64 + sseg * 16
                : x + (size_t)(r0 + srow) * E_DIM + (kb - 2) * 64 + sseg * 16;
            const float4* p = (const float4*)src;
            float4 v0 = p[0], v1 = p[1], v2 = p[2], v3 = p[3];
            ushort8 h0 = { f2bf(v0.x), f2bf(v0.y), f2bf(v0.z), f2bf(v0.w),
                           f2bf(v1.x), f2bf(v1.y), f2bf(v1.z), f2bf(v1.w) };
            ushort8 h1 = { f2bf(v2.x), f2bf(v2.y), f2bf(v2.z), f2bf(v2.w),
                           f2bf(v3.x), f2bf(v3.y), f2bf(v3.z), f2bf(v3.w) };
            int b0 = srow * 128 + ((sseg * 32) ^ ((srow & 7) << 4));
            *(ushort8*)((char*)Asub + b0)        = h0;
            *(ushort8*)((char*)Asub + (b0 ^ 16)) = h1;
        }
        __syncthreads();
#pragma unroll
        for (int ks = 0; ks < 2; ++ks) {
            bf16x8 af[4];
#pragma unroll
            for (int rf = 0; rf < 4; ++rf) {
                int r  = rf * 16 + lr;
                int bo = r * 128 + (((ks * 64) + q * 16) ^ ((r & 7) << 4));
                af[rf] = *(const bf16x8*)((const char*)Asub + bo);
            }
#pragma unroll
            for (int cgl = 0; cgl < 4; ++cgl) {
                int c = (w + cgl * 4) * 16 + lr;
                const unsigned short* wp = (kb < 2)
                    ? wtCellH + ((size_t)l * 256 + c) * 128 + kb * 64 + ks * 32 + q * 8
                    : wtInpH + (size_t)c * 256 + (kb - 2) * 64 + ks * 32 + q * 8;
                bf16x8 bfr = *(const bf16x8*)wp;
#pragma unroll
                for (int rf = 0; rf < 4; ++rf)
                    accH[rf][cgl] = __builtin_amdgcn_mfma_f32_16x16x32_bf16(
                        af[rf], bfr, accH[rf][cgl], 0, 0, 0);
            }
        }
    }

    // ================= P2: hyper highway gate; write sH (f32 out + bf16 LDS) =================
#pragma unroll
    for (int cgl = 0; cgl < 2; ++cgl) {
        int ch = (w + cgl * 4) * 16 + lr;     // 0..127
        float bh = b_cell_h[l * 256 + ch]       + ((l == 0) ? b_inp_h[ch]       : 0.f);
        float bt = b_cell_h[l * 256 + 128 + ch] + ((l == 0) ? b_inp_h[128 + ch] : 0.f);
#pragma unroll
        for (int rf = 0; rf < 4; ++rf)
#pragma unroll
            for (int i = 0; i < 4; ++i) {
                int r = rf * 16 + q * 4 + i;
                size_t gr = (size_t)l * B_ROWS + r0 + r;
                float a = accH[rf][cgl][i]     + bh;
                float g = accH[rf][cgl + 2][i] + bt;
                float hh = fast_tanh(a);
                float tt = fast_sig(g);
                float sold = sHyper[gr * HH_DIM + ch];
                float sh = hh * tt + sold * (1.0f - tt);
                outSH[gr * HH_DIM + ch] = sh;
                int bo = r * 256 + ((ch * 2) ^ ((r & 7) << 4));
                *(unsigned short*)((char*)sHlds + bo) = f2bf(sh);
            }
    }
    __syncthreads();

    // ================= P4-accum: T = sNetwork[l] @ W_cell_n[l] (+ x @ W_inp_n at l==0) =================
    f32x4 accT[4][8] = {};   // cg = (cgl<4) ? w+cgl*4 : 16 + w + (cgl-4)*4
    const int nkb4 = (l == 0) ? 8 : 4;
    for (int kb = 0; kb < nkb4; ++kb) {
        __syncthreads();
        {
            const float* src = (kb < 4)
                ? sNetwork + ((size_t)l * B_ROWS + r0 + srow) * HN_DIM + kb * 64 + sseg * 16
                : x + (size_t)(r0 + srow) * E_DIM + (kb - 4) * 64 + sseg * 16;
            const float4* p = (const float4*)src;
            float4 v0 = p[0], v1 = p[1], v2 = p[2], v3 = p[3];
            ushort8 h0 = { f2bf(v0.x), f2bf(v0.y), f2bf(v0.z), f2bf(v0.w),
                           f2bf(v1.x), f2bf(v1.y), f2bf(v1.z), f2bf(v1.w) };
            ushort8 h1 = { f2bf(v2.x), f2bf(v2.y), f2bf(v2.z), f2bf(v2.w),
                           f2bf(v3.x), f2bf(v3.y), f2bf(v3.z), f2bf(v3.w) };
            int b0 = srow * 128 + ((sseg * 32) ^ ((srow & 7) << 4));
            *(ushort8*)((char*)Asub + b0)        = h0;
            *(ushort8*)((char*)Asub + (b0 ^ 16)) = h1;
        }
        __syncthreads();
#pragma unroll
        for (int ks = 0; ks < 2; ++ks) {
            bf16x8 af[4];
#pragma unroll
            for (int rf = 0; rf < 4; ++rf) {
                int r  = rf * 16 + lr;
                int bo = r * 128 + (((ks * 64) + q * 16) ^ ((r & 7) << 4));
                af[rf] = *(const bf16x8*)((const char*)Asub + bo);
            }
#pragma unroll
            for (int cgl = 0; cgl < 8; ++cgl) {
                int cgi = (cgl < 4) ? (w + cgl * 4) : (16 + w + (cgl - 4) * 4);
                int c = cgi * 16 + lr;
                const unsigned short* wp = (kb < 4)
                    ? wtCellN + ((size_t)l * 512 + c) * 256 + kb * 64 + ks * 32 + q * 8
                    : wtInpN + (size_t)c * 256 + (kb - 4) * 64 + ks * 32 + q * 8;
                bf16x8 bfr = *(const bf16x8*)wp;
#pragma unroll
                for (int rf = 0; rf < 4; ++rf)
                    accT[rf][cgl] = __builtin_amdgcn_mfma_f32_16x16x32_bf16(
                        af[rf], bfr, accT[rf][cgl], 0, 0, 0);
            }
        }
    }

    // ================= P3 + epilogue: per col-group, z = sH @ W_up[l], then gate =================
#pragma unroll
    for (int cgl = 0; cgl < 4; ++cgl) {
        int cz = (w + cgl * 4) * 16 + lr;     // z col == T hh col; T tt col = cz + 256
        f32x4 zac[4] = {};
#pragma unroll
        for (int ks = 0; ks < 4; ++ks) {
            const unsigned short* wp = wtUp + ((size_t)l * 256 + cz) * 128 + ks * 32 + q * 8;
            bf16x8 bfr = *(const bf16x8*)wp;
#pragma unroll
            for (int rf = 0; rf < 4; ++rf) {
                int r  = rf * 16 + lr;
                int bo = r * 256 + (((ks * 64) + q * 16) ^ ((r & 7) << 4));
                bf16x8 afr = *(const bf16x8*)((const char*)sHlds + bo);
                zac[rf] = __builtin_amdgcn_mfma_f32_16x16x32_bf16(afr, bfr, zac[rf], 0, 0, 0);
            }
        }
        float bz  = b_up[l * 256 + cz];
        float bhn = b_cell_n[l * 512 + cz]       + ((l == 0) ? b_inp_n[cz]       : 0.f);
        float btn = b_cell_n[l * 512 + 256 + cz] + ((l == 0) ? b_inp_n[256 + cz] : 0.f);
#pragma unroll
        for (int rf = 0; rf < 4; ++rf)
#pragma unroll
            for (int i = 0; i < 4; ++i) {
                int r = rf * 16 + q * 4 + i;
                size_t gr = (size_t)l * B_ROWS + r0 + r;
                float zi = zac[rf][i] + bz;
                float tpre = zi * (accT[rf][cgl][i]     + bhn);
                float upre = zi * (accT[rf][cgl + 4][i] + btn);
                float hh = fast_tanh(tpre);
                float tt = fast_sig(upre);
                float sold = sNetwork[gr * HN_DIM + cz];
                float sn = hh * tt + sold * (1.0f - tt);
                outSN[gr * HN_DIM + cz] = sn;
                if (l == 4) outMain[(size_t)(r0 + r) * HN_DIM + cz] = sn;
            }
    }
}

extern "C" void kernel_launch(void* const* d_in, const int* in_sizes, int n_in,
                              void* d_out, int out_size, void* d_ws, size_t ws_size,
                              hipStream_t stream) {
    const float* x        = (const float*)d_in[0];
    const float* sHyper   = (const float*)d_in[1];
    const float* sNetwork = (const float*)d_in[2];
    const float* W_inp_h  = (const float*)d_in[3];
    const float* b_inp_h  = (const float*)d_in[4];
    const float* W_cell_h = (const float*)d_in[5];
    const float* b_cell_h = (const float*)d_in[6];
    const float* W_inp_n  = (const float*)d_in[7];
    const float* b_inp_n  = (const float*)d_in[8];
    const float* W_cell_n = (const float*)d_in[9];
    const float* b_cell_n = (const float*)d_in[10];
    const float* W_up     = (const float*)d_in[11];
    const float* b_up     = (const float*)d_in[12];

    unsigned short* ws = (unsigned short*)d_ws;
    unsigned short* wtCellH = ws;                  // [5][256][128]
    unsigned short* wtUp    = ws + 163840;         // [5][256][128]
    unsigned short* wtCellN = ws + 327680;         // [5][512][256]
    unsigned short* wtInpH  = ws + 983040;         // [256][256]
    unsigned short* wtInpN  = ws + 1048576;        // [512][256]
    // total 1,179,648 ushorts = 2.36 MB of d_ws

    dim3 tb(32, 8);
    wtrans_kernel<<<dim3(256 / 32, 128 / 32, 5), tb, 0, stream>>>(W_cell_h, wtCellH, 128, 256);
    wtrans_kernel<<<dim3(256 / 32, 128 / 32, 5), tb, 0, stream>>>(W_up,     wtUp,    128, 256);
    wtrans_kernel<<<dim3(512 / 32, 256 / 32, 5), tb, 0, stream>>>(W_cell_n, wtCellN, 256, 512);
    wtrans_kernel<<<dim3(256 / 32, 256 / 32, 1), tb, 0, stream>>>(W_inp_h,  wtInpH,  256, 256);
    wtrans_kernel<<<dim3(512 / 32, 256 / 32, 1), tb, 0, stream>>>(W_inp_n,  wtInpN,  256, 512);

    float* outMain = (float*)d_out;
    float* outSH = outMain + (size_t)B_ROWS * HN_DIM;                 // [5][B][128]
    float* outSN = outSH + (size_t)NDEPTH * B_ROWS * HH_DIM;          // [5][B][256]

    hyper_rhn_kernel<<<dim3(B_ROWS / 64, NDEPTH), 256, 0, stream>>>(
        x, sHyper, sNetwork,
        b_inp_h, b_cell_h, b_inp_n, b_cell_n, b_up,
        wtCellH, wtUp, wtCellN, wtInpH, wtInpN,
        outMain, outSH, outSN);
}